// Round 1
// baseline (988.365 us; speedup 1.0000x reference)
//
#include <hip/hip_runtime.h>
#include <cfloat>

// Problem constants
#define B_   16
#define C_   256
#define HW_  4096      // 64*64
#define N_   65536     // B_*HW_
#define K_   1024

// Output layout (float32, concatenated flat in return order):
//  [0]                      loss
//  [1, 1+16777216)          quantized_out  (b c h w)
//  [16777217]               perplexity
//  [16777218, +67108864)    encodings      (N, K) one-hot
#define OUT_QOFF   1
#define OUT_POFF   16777217
#define OUT_EOFF   16777218

// Workspace layout (bytes):
//  [0,       262144)   int   bestIdx[N]
//  [262144,  266240)   int   counts[K]
//  [266240,  282624)   float partials[4096]
//  [282624, 1331200)   float embT[C][K]     (1 MB)
//  [1331200,1335296)   float enorm[K]

// ---------------------------------------------------------------- transpose
__global__ __launch_bounds__(256) void k_transpose(const float* __restrict__ emb,
                                                   float* __restrict__ embT) {
    int i = blockIdx.x * 256 + threadIdx.x;   // i = k*C + c, coalesced read
    int k = i >> 8;
    int c = i & 255;
    embT[c * K_ + k] = emb[i];
}

// ------------------------------------------------------- ||e||^2 + zero cnt
__global__ __launch_bounds__(256) void k_enorm(const float* __restrict__ emb,
                                               float* __restrict__ enorm,
                                               int* __restrict__ counts) {
    int k = blockIdx.x * 256 + threadIdx.x;   // 4 blocks -> k in [0,1024)
    const float4* e4 = (const float4*)(emb + (size_t)k * C_);
    float s = 0.f;
#pragma unroll 8
    for (int j = 0; j < C_ / 4; ++j) {
        float4 v = e4[j];
        s += v.x * v.x + v.y * v.y + v.z * v.z + v.w * v.w;
    }
    enorm[k] = s;
    counts[k] = 0;
}

// ------------------------------------------------------------ argmin "GEMM"
// One block = 64 rows (contiguous hw within one b). X^T tile staged in LDS
// (64 KB). Loop K in 16 tiles of 64; each thread computes a 4x4 micro-tile,
// B read directly from L2-resident embT (contiguous 64-float slices).
__global__ __launch_bounds__(256) void k_argmin(const float* __restrict__ x,
                                                const float* __restrict__ embT,
                                                const float* __restrict__ enorm,
                                                int* __restrict__ bestIdx,
                                                int* __restrict__ counts) {
    __shared__ float A[C_][64];               // [c][row] fp32, 64 KB

    const int tid  = threadIdx.x;
    const int tx   = tid & 15;                // 4 codes each
    const int ty   = tid >> 4;                // 4 rows each
    const int row0 = blockIdx.x * 64;
    const int xbase = (row0 >> 12) * (C_ * HW_) + (row0 & 4095);

    // stage X^T tile: coalesced float4 loads (hw contiguous per channel plane)
    for (int i = tid; i < C_ * 16; i += 256) {
        int c  = i >> 4;
        int rq = (i & 15) << 2;
        float4 v = *(const float4*)&x[xbase + c * HW_ + rq];
        *(float4*)&A[c][rq] = v;
    }
    __syncthreads();

    float best[4] = {FLT_MAX, FLT_MAX, FLT_MAX, FLT_MAX};
    int   bidx[4] = {0, 0, 0, 0};
    const int ty4 = ty << 2;

    for (int kt = 0; kt < 16; ++kt) {
        const int k0 = kt * 64 + (tx << 2);
        const float* bp = embT + k0;
        float acc[4][4];
#pragma unroll
        for (int i = 0; i < 4; ++i)
#pragma unroll
            for (int j = 0; j < 4; ++j) acc[i][j] = 0.f;

#pragma unroll 4
        for (int c = 0; c < C_; ++c) {
            float4 av = *(const float4*)&A[c][ty4];
            float4 bv = *(const float4*)&bp[c * K_];
            float a[4] = {av.x, av.y, av.z, av.w};
            float b[4] = {bv.x, bv.y, bv.z, bv.w};
#pragma unroll
            for (int i = 0; i < 4; ++i)
#pragma unroll
                for (int j = 0; j < 4; ++j)
                    acc[i][j] = fmaf(a[i], b[j], acc[i][j]);
        }

        float4 env = *(const float4*)&enorm[k0];
        float en[4] = {env.x, env.y, env.z, env.w};
#pragma unroll
        for (int i = 0; i < 4; ++i)
#pragma unroll
            for (int j = 0; j < 4; ++j) {
                float d = en[j] - 2.0f * acc[i][j];     // + ||x||^2 is a per-row const
                if (d < best[i]) { best[i] = d; bidx[i] = k0 + j; }
            }
    }

    // cross-lane argmin over the 16 tx lanes (consecutive lanes in-wave);
    // ties -> smaller index (np.argmin first-occurrence semantics)
#pragma unroll
    for (int i = 0; i < 4; ++i) {
        float v  = best[i];
        int   id = bidx[i];
#pragma unroll
        for (int m = 1; m < 16; m <<= 1) {
            float ov = __shfl_xor(v, m);
            int   oi = __shfl_xor(id, m);
            if (ov < v || (ov == v && oi < id)) { v = ov; id = oi; }
        }
        if (tx == 0) {
            int n = row0 + ty4 + i;
            bestIdx[n] = id;
            atomicAdd(&counts[id], 1);
        }
    }
}

// --------------------------------------------- gather quantized + loss part
__global__ __launch_bounds__(256) void k_quant(const float* __restrict__ x,
                                               const float* __restrict__ emb,
                                               const int* __restrict__ bestIdx,
                                               float* __restrict__ outq,   // d_out+1
                                               float* __restrict__ partials) {
    const int tid = threadIdx.x;
    float lsum = 0.f;
#pragma unroll
    for (int it = 0; it < 4; ++it) {
        int q  = blockIdx.x * 256 + tid + it * (4096 * 256);
        int f  = q << 2;                       // flat index into (b c hw)
        int hw = f & 4095;
        int c  = (f >> 12) & 255;
        int b  = f >> 20;
        int n0 = (b << 12) + hw;
        int4  id = *(const int4*)&bestIdx[n0];
        float4 xv = *(const float4*)&x[f];
        float q0 = emb[id.x * C_ + c];
        float q1 = emb[id.y * C_ + c];
        float q2 = emb[id.z * C_ + c];
        float q3 = emb[id.w * C_ + c];
        // straight-through: x + (q - x)  (matches reference rounding)
        outq[f + 0] = xv.x + (q0 - xv.x);
        outq[f + 1] = xv.y + (q1 - xv.y);
        outq[f + 2] = xv.z + (q2 - xv.z);
        outq[f + 3] = xv.w + (q3 - xv.w);
        float d0 = q0 - xv.x, d1 = q1 - xv.y, d2 = q2 - xv.z, d3 = q3 - xv.w;
        lsum += d0 * d0 + d1 * d1 + d2 * d2 + d3 * d3;
    }
    // deterministic block reduction
    __shared__ float red[4];
#pragma unroll
    for (int o = 32; o > 0; o >>= 1) lsum += __shfl_down(lsum, o);
    if ((tid & 63) == 0) red[tid >> 6] = lsum;
    __syncthreads();
    if (tid == 0) partials[blockIdx.x] = (red[0] + red[1]) + (red[2] + red[3]);
}

// ------------------------------------------------------- one-hot encodings
__global__ __launch_bounds__(256) void k_enc(const int* __restrict__ bestIdx,
                                             float* __restrict__ enc) {   // d_out+EOFF
    for (int row = blockIdx.x; row < N_; row += 8192) {
        int idv = bestIdx[row];
        size_t base = (size_t)row * K_;
#pragma unroll
        for (int j = 0; j < 4; ++j) {
            int k = threadIdx.x + j * 256;
            enc[base + k] = (k == idv) ? 1.0f : 0.0f;
        }
    }
}

// ----------------------------------------------------------------- finalize
__global__ __launch_bounds__(256) void k_final(const float* __restrict__ partials,
                                               const int* __restrict__ counts,
                                               float* __restrict__ out) {
    const int tid = threadIdx.x;
    float s = 0.f;
    for (int i = tid; i < 4096; i += 256) s += partials[i];
    float h = 0.f;
    for (int k = tid; k < K_; k += 256) {
        float p = (float)counts[k] * (1.0f / 65536.0f);
        h += p * logf(p + 1e-10f);
    }
    __shared__ float redS[4], redH[4];
#pragma unroll
    for (int o = 32; o > 0; o >>= 1) {
        s += __shfl_down(s, o);
        h += __shfl_down(h, o);
    }
    if ((tid & 63) == 0) { redS[tid >> 6] = s; redH[tid >> 6] = h; }
    __syncthreads();
    if (tid == 0) {
        float S = (redS[0] + redS[1]) + (redS[2] + redS[3]);
        float H = (redH[0] + redH[1]) + (redH[2] + redH[3]);
        out[0]        = 0.25f * S / 16777216.0f;   // commitment_cost * mean
        out[OUT_POFF] = expf(-H);
    }
}

extern "C" void kernel_launch(void* const* d_in, const int* in_sizes, int n_in,
                              void* d_out, int out_size, void* d_ws, size_t ws_size,
                              hipStream_t stream) {
    const float* x   = (const float*)d_in[0];
    const float* emb = (const float*)d_in[1];
    float* out = (float*)d_out;
    char*  ws  = (char*)d_ws;

    int*   bestIdx  = (int*)(ws);
    int*   counts   = (int*)(ws + 262144);
    float* partials = (float*)(ws + 266240);
    float* embT     = (float*)(ws + 282624);
    float* enorm    = (float*)(ws + 1331200);

    k_transpose<<<K_ * C_ / 256, 256, 0, stream>>>(emb, embT);
    k_enorm    <<<K_ / 256,      256, 0, stream>>>(emb, enorm, counts);
    k_argmin   <<<N_ / 64,       256, 0, stream>>>(x, embT, enorm, bestIdx, counts);
    k_quant    <<<4096,          256, 0, stream>>>(x, emb, bestIdx, out + OUT_QOFF, partials);
    k_enc      <<<8192,          256, 0, stream>>>(bestIdx, out + OUT_EOFF);
    k_final    <<<1,             256, 0, stream>>>(partials, counts, out);
}

// Round 3
// 303.568 us; speedup vs baseline: 3.2558x; 3.2558x over previous
//
#include <hip/hip_runtime.h>
#include <cfloat>

// Problem constants
#define B_   16
#define C_   256
#define HW_  4096      // 64*64
#define N_   65536     // B_*HW_
#define K_   1024

// Output layout (float32, concatenated flat in return order):
//  [0] loss | [1,+16777216) quantized (b c h w) | [16777217] perplexity
//  [16777218,+67108864) encodings (N,K)
#define OUT_QOFF   1
#define OUT_POFF   16777217
#define OUT_EOFF   16777218

typedef __bf16 bf16x8 __attribute__((ext_vector_type(8)));
typedef float  f32x4  __attribute__((ext_vector_type(4)));

// ---------------------------------------------------------------- bf16 split
__device__ inline ushort f2bf(float f) {
    union { float f; unsigned u; } a; a.f = f;
    unsigned u = a.u;
    unsigned r = (u + 0x7fffu + ((u >> 16) & 1u)) >> 16;   // RNE
    return (ushort)r;
}
__device__ inline float bf2f(ushort u) {
    union { float f; unsigned u; } a; a.u = ((unsigned)u) << 16; return a.f;
}
__device__ inline void split3(float x, ushort& h, ushort& m, ushort& l) {
    h = f2bf(x);
    float r1 = x - bf2f(h);
    m = f2bf(r1);
    float r2 = r1 - bf2f(m);
    l = f2bf(r2);
}

// -------------------------------------------------- pack e into MFMA order
// Layout: per step s in [0,64) (k-tile kt=s>>1 of 32 codes, c-half h=s&1 of
// 128 ch): 24576-byte block = [split(3)][cg(16)][code(32)][ci(8)] bf16.
__global__ __launch_bounds__(256) void k_pack_e(const float* __restrict__ emb,
                                                char* __restrict__ epk) {
    int i = blockIdx.x * 256 + threadIdx.x;   // i = k*256 + c
    int k = i >> 8, c = i & 255;
    ushort h, m, l;
    split3(emb[i], h, m, l);
    size_t blk = (size_t)((k >> 5) * 2 + (c >> 7)) * 24576;
    size_t off = blk + (size_t)(((c & 127) >> 3) * 512 + (k & 31) * 16 + (c & 7) * 2);
    *(ushort*)(epk + off)         = h;
    *(ushort*)(epk + off + 8192)  = m;
    *(ushort*)(epk + off + 16384) = l;
}

// ------------------------------------------------------- ||e||^2 + zero cnt
__global__ __launch_bounds__(256) void k_enorm(const float* __restrict__ emb,
                                               float* __restrict__ enorm,
                                               int* __restrict__ counts) {
    int k = blockIdx.x * 256 + threadIdx.x;
    const float4* e4 = (const float4*)(emb + (size_t)k * C_);
    float s = 0.f;
#pragma unroll 8
    for (int j = 0; j < C_ / 4; ++j) {
        float4 v = e4[j];
        s += v.x * v.x + v.y * v.y + v.z * v.z + v.w * v.w;
    }
    enorm[k] = s;
    counts[k] = 0;
}

// --------------------------------------------------------- MFMA argmin GEMM
// Block: 64 rows x 1024 codes, 4 waves (16 rows each). A (3 bf16 splits) in
// registers; B double-buffered in LDS via global_load_lds; 6-product fp32
// emulation; per-lane running argmin, first-occurrence tie-break.
__global__ __launch_bounds__(256, 3) void k_argmin_mfma(const float* __restrict__ x,
                                                        const char* __restrict__ epk,
                                                        const float* __restrict__ enorm,
                                                        int* __restrict__ bestIdx,
                                                        int* __restrict__ counts) {
    __shared__ __align__(16) char Bs[2][24576];
    __shared__ float En[K_];

    const int tid  = threadIdx.x;
    const int lane = tid & 63;
    const int wid  = tid >> 6;
    const int l15  = lane & 15;
    const int kg   = lane >> 4;
    const int row0 = blockIdx.x * 64;
    const int cpOff = wid * 1024 + lane * 16;   // this wave's copy offset

    // ---- stage enorm to LDS
    for (int i = tid; i < K_; i += 256) En[i] = enorm[i];

    // ---- build A fragments in registers (row = l15, k-elems = kg*8+i)
    union FU { bf16x8 v; ushort u[8]; };
    FU Ah[8], Am[8], Al[8];
    {
        const int n  = row0 + wid * 16 + l15;
        const int b  = n >> 12, hw = n & 4095;
        const float* xb = x + (size_t)b * (C_ * HW_) + hw;
#pragma unroll
        for (int cb = 0; cb < 8; ++cb) {
#pragma unroll
            for (int i = 0; i < 8; ++i) {
                float v = xb[(cb * 32 + kg * 8 + i) * HW_];
                ushort h, m, l;
                split3(v, h, m, l);
                Ah[cb].u[i] = h; Am[cb].u[i] = m; Al[cb].u[i] = l;
            }
        }
    }
    __syncthreads();   // drains vmcnt(0)+lgkmcnt(0): clean slate for counting

    // ---- stage step 0 (src and dst MUST share the same offset: cpOff+j*4096)
    {
        const char* src = epk + (size_t)cpOff;
        char* dstb = &Bs[0][0] + cpOff;
#pragma unroll
        for (int j = 0; j < 6; ++j) {
            __builtin_amdgcn_global_load_lds(
                (const __attribute__((address_space(1))) void*)(src + j * 4096),
                (__attribute__((address_space(3))) void*)(dstb + j * 4096), 16, 0, 0);
        }
    }

    float best[4] = {FLT_MAX, FLT_MAX, FLT_MAX, FLT_MAX};
    int   bidx[4] = {0, 0, 0, 0};
    const int laneB = kg * 512 + l15 * 16;
    const f32x4 zero = {0.f, 0.f, 0.f, 0.f};
    f32x4 accA, accB;

#define STEP(H, IS_LAST) do {                                                     \
    if (!(IS_LAST)) {                                                             \
        int sn = 2 * kt + (H) + 1;                                                \
        const char* src = epk + (size_t)sn * 24576 + (size_t)cpOff;               \
        char* dstb = &Bs[1 - (H)][0] + cpOff;                                     \
        _Pragma("unroll")                                                         \
        for (int j = 0; j < 6; ++j) {                                             \
            __builtin_amdgcn_global_load_lds(                                     \
                (const __attribute__((address_space(1))) void*)(src + j * 4096),  \
                (__attribute__((address_space(3))) void*)(dstb + j * 4096),       \
                16, 0, 0);                                                        \
        }                                                                         \
        asm volatile("s_waitcnt vmcnt(6)" ::: "memory");                          \
    } else {                                                                      \
        asm volatile("s_waitcnt vmcnt(0)" ::: "memory");                          \
    }                                                                             \
    __builtin_amdgcn_s_barrier();                                                 \
    asm volatile("" ::: "memory");                                                \
    {                                                                             \
        const char* bbase = &Bs[(H)][0] + laneB;                                  \
        _Pragma("unroll")                                                         \
        for (int cbl = 0; cbl < 4; ++cbl) {                                       \
            const char* bp = bbase + cbl * 2048;                                  \
            bf16x8 Bh0 = *(const bf16x8*)(bp);                                    \
            bf16x8 Bm0 = *(const bf16x8*)(bp + 8192);                             \
            bf16x8 Bl0 = *(const bf16x8*)(bp + 16384);                            \
            bf16x8 Bh1 = *(const bf16x8*)(bp + 256);                              \
            bf16x8 Bm1 = *(const bf16x8*)(bp + 8448);                             \
            bf16x8 Bl1 = *(const bf16x8*)(bp + 16640);                            \
            const bf16x8 ah = Ah[(H) * 4 + cbl].v;                                \
            const bf16x8 am = Am[(H) * 4 + cbl].v;                                \
            const bf16x8 al = Al[(H) * 4 + cbl].v;                                \
            accA = __builtin_amdgcn_mfma_f32_16x16x32_bf16(ah, Bh0, accA, 0,0,0); \
            accB = __builtin_amdgcn_mfma_f32_16x16x32_bf16(ah, Bh1, accB, 0,0,0); \
            accA = __builtin_amdgcn_mfma_f32_16x16x32_bf16(ah, Bm0, accA, 0,0,0); \
            accB = __builtin_amdgcn_mfma_f32_16x16x32_bf16(ah, Bm1, accB, 0,0,0); \
            accA = __builtin_amdgcn_mfma_f32_16x16x32_bf16(am, Bh0, accA, 0,0,0); \
            accB = __builtin_amdgcn_mfma_f32_16x16x32_bf16(am, Bh1, accB, 0,0,0); \
            accA = __builtin_amdgcn_mfma_f32_16x16x32_bf16(am, Bm0, accA, 0,0,0); \
            accB = __builtin_amdgcn_mfma_f32_16x16x32_bf16(am, Bm1, accB, 0,0,0); \
            accA = __builtin_amdgcn_mfma_f32_16x16x32_bf16(ah, Bl0, accA, 0,0,0); \
            accB = __builtin_amdgcn_mfma_f32_16x16x32_bf16(ah, Bl1, accB, 0,0,0); \
            accA = __builtin_amdgcn_mfma_f32_16x16x32_bf16(al, Bh0, accA, 0,0,0); \
            accB = __builtin_amdgcn_mfma_f32_16x16x32_bf16(al, Bh1, accB, 0,0,0); \
        }                                                                         \
    }                                                                             \
    asm volatile("s_waitcnt lgkmcnt(0)" ::: "memory");                            \
    __builtin_amdgcn_s_barrier();                                                 \
} while (0)

    for (int kt = 0; kt < 32; ++kt) {
        accA = zero; accB = zero;
        STEP(0, false);
        STEP(1, kt == 31);
        // fold: lane holds cols cA = kt*32+l15 (tile0), cB = cA+16 (tile1);
        // rows = kg*4 + r. Ascending k + strict < => first-occurrence.
        const int cA = kt * 32 + l15;
        const int cB = cA + 16;
        const float enA = En[cA], enB = En[cB];
#pragma unroll
        for (int r = 0; r < 4; ++r) {
            float dA = enA - 2.0f * accA[r];
            if (dA < best[r]) { best[r] = dA; bidx[r] = cA; }
            float dB = enB - 2.0f * accB[r];
            if (dB < best[r]) { best[r] = dB; bidx[r] = cB; }
        }
    }
#undef STEP

    // cross-lane argmin over the 16 cols (lanes sharing kg group)
#pragma unroll
    for (int r = 0; r < 4; ++r) {
        float v  = best[r];
        int   id = bidx[r];
#pragma unroll
        for (int m = 1; m < 16; m <<= 1) {
            float ov = __shfl_xor(v, m);
            int   oi = __shfl_xor(id, m);
            if (ov < v || (ov == v && oi < id)) { v = ov; id = oi; }
        }
        if (l15 == 0) {
            int n = row0 + wid * 16 + kg * 4 + r;
            bestIdx[n] = id;
            atomicAdd(&counts[id], 1);
        }
    }
}

// --------------------------------------------- gather quantized + loss part
__global__ __launch_bounds__(256) void k_quant(const float* __restrict__ x,
                                               const float* __restrict__ emb,
                                               const int* __restrict__ bestIdx,
                                               float* __restrict__ outq,
                                               float* __restrict__ partials) {
    const int tid = threadIdx.x;
    float lsum = 0.f;
#pragma unroll
    for (int it = 0; it < 4; ++it) {
        int q  = blockIdx.x * 256 + tid + it * (4096 * 256);
        int f  = q << 2;
        int hw = f & 4095;
        int c  = (f >> 12) & 255;
        int b  = f >> 20;
        int n0 = (b << 12) + hw;
        int4  id = *(const int4*)&bestIdx[n0];
        float4 xv = *(const float4*)&x[f];
        float q0 = emb[id.x * C_ + c];
        float q1 = emb[id.y * C_ + c];
        float q2 = emb[id.z * C_ + c];
        float q3 = emb[id.w * C_ + c];
        outq[f + 0] = xv.x + (q0 - xv.x);
        outq[f + 1] = xv.y + (q1 - xv.y);
        outq[f + 2] = xv.z + (q2 - xv.z);
        outq[f + 3] = xv.w + (q3 - xv.w);
        float d0 = q0 - xv.x, d1 = q1 - xv.y, d2 = q2 - xv.z, d3 = q3 - xv.w;
        lsum += d0 * d0 + d1 * d1 + d2 * d2 + d3 * d3;
    }
    __shared__ float red[4];
#pragma unroll
    for (int o = 32; o > 0; o >>= 1) lsum += __shfl_down(lsum, o);
    if ((tid & 63) == 0) red[tid >> 6] = lsum;
    __syncthreads();
    if (tid == 0) partials[blockIdx.x] = (red[0] + red[1]) + (red[2] + red[3]);
}

// ------------------------------------------------------- one-hot encodings
__global__ __launch_bounds__(256) void k_enc(const int* __restrict__ bestIdx,
                                             float* __restrict__ enc) {
    for (int row = blockIdx.x; row < N_; row += 8192) {
        int idv = bestIdx[row];
        size_t base = (size_t)row * K_;
#pragma unroll
        for (int j = 0; j < 4; ++j) {
            int k = threadIdx.x + j * 256;
            enc[base + k] = (k == idv) ? 1.0f : 0.0f;
        }
    }
}

// ----------------------------------------------------------------- finalize
__global__ __launch_bounds__(256) void k_final(const float* __restrict__ partials,
                                               const int* __restrict__ counts,
                                               float* __restrict__ out) {
    const int tid = threadIdx.x;
    float s = 0.f;
    for (int i = tid; i < 4096; i += 256) s += partials[i];
    float h = 0.f;
    for (int k = tid; k < K_; k += 256) {
        float p = (float)counts[k] * (1.0f / 65536.0f);
        h += p * logf(p + 1e-10f);
    }
    __shared__ float redS[4], redH[4];
#pragma unroll
    for (int o = 32; o > 0; o >>= 1) {
        s += __shfl_down(s, o);
        h += __shfl_down(h, o);
    }
    if ((tid & 63) == 0) { redS[tid >> 6] = s; redH[tid >> 6] = h; }
    __syncthreads();
    if (tid == 0) {
        float S = (redS[0] + redS[1]) + (redS[2] + redS[3]);
        float H = (redH[0] + redH[1]) + (redH[2] + redH[3]);
        out[0]        = 0.25f * S / 16777216.0f;
        out[OUT_POFF] = expf(-H);
    }
}

extern "C" void kernel_launch(void* const* d_in, const int* in_sizes, int n_in,
                              void* d_out, int out_size, void* d_ws, size_t ws_size,
                              hipStream_t stream) {
    const float* x   = (const float*)d_in[0];
    const float* emb = (const float*)d_in[1];
    float* out = (float*)d_out;
    char*  ws  = (char*)d_ws;

    // Workspace layout
    int*   bestIdx  = (int*)(ws);                 // 262144 B
    int*   counts   = (int*)(ws + 262144);        //   4096 B
    float* partials = (float*)(ws + 266240);      //  16384 B
    float* enorm    = (float*)(ws + 282624);      //   4096 B
    char*  epk      = ws + 286720;                // 1572864 B packed e-splits

    k_pack_e     <<<K_ * C_ / 256, 256, 0, stream>>>(emb, epk);
    k_enorm      <<<K_ / 256,      256, 0, stream>>>(emb, enorm, counts);
    k_argmin_mfma<<<N_ / 64,       256, 0, stream>>>(x, epk, enorm, bestIdx, counts);
    k_quant      <<<4096,          256, 0, stream>>>(x, emb, bestIdx, out + OUT_QOFF, partials);
    k_enc        <<<8192,          256, 0, stream>>>(bestIdx, out + OUT_EOFF);
    k_final      <<<1,             256, 0, stream>>>(partials, counts, out);
}

// Round 4
// 261.551 us; speedup vs baseline: 3.7789x; 1.1606x over previous
//
#include <hip/hip_runtime.h>
#include <cfloat>

// Problem constants
#define B_   16
#define C_   256
#define HW_  4096      // 64*64
#define N_   65536     // B_*HW_
#define K_   1024

// Output layout (float32, concatenated flat in return order):
//  [0] loss | [1,+16777216) quantized (b c h w) | [16777217] perplexity
//  [16777218,+67108864) encodings (N,K)
#define OUT_QOFF   1
#define OUT_POFF   16777217
#define OUT_EOFF   16777218

typedef __bf16 bf16x8 __attribute__((ext_vector_type(8)));
typedef float  f32x4  __attribute__((ext_vector_type(4)));

// ---------------------------------------------------------------- bf16 split
__device__ inline ushort f2bf(float f) {
    union { float f; unsigned u; } a; a.f = f;
    unsigned u = a.u;
    unsigned r = (u + 0x7fffu + ((u >> 16) & 1u)) >> 16;   // RNE
    return (ushort)r;
}
__device__ inline float bf2f(ushort u) {
    union { float f; unsigned u; } a; a.u = ((unsigned)u) << 16; return a.f;
}
__device__ inline void split3(float x, ushort& h, ushort& m, ushort& l) {
    h = f2bf(x);
    float r1 = x - bf2f(h);
    m = f2bf(r1);
    float r2 = r1 - bf2f(m);
    l = f2bf(r2);
}

// -------------------------------------------------- pack e into MFMA order
// e uses a 2-way split (h, m). Per step s in [0,64) (k-tile kt=s>>1 of 32
// codes, c-half h2=s&1 of 128 ch): 16384-byte block =
// [split(2)][cg(16)][code(32)][ci(8)] bf16 (8 KB per split plane).
__global__ __launch_bounds__(256) void k_pack_e(const float* __restrict__ emb,
                                                char* __restrict__ epk) {
    int i = blockIdx.x * 256 + threadIdx.x;   // i = k*256 + c
    int k = i >> 8, c = i & 255;
    ushort h, m, l;
    split3(emb[i], h, m, l);
    (void)l;                                   // e_l dropped (5-product scheme)
    int s  = (k >> 5) * 2 + (c >> 7);
    int cl = c & 127;
    size_t off = (size_t)s * 16384 + (size_t)((cl >> 3) * 512 + (k & 31) * 16 + (cl & 7) * 2);
    *(ushort*)(epk + off)        = h;
    *(ushort*)(epk + off + 8192) = m;
}

// ------------------------------------------------------- ||e||^2 + zero cnt
__global__ __launch_bounds__(256) void k_enorm(const float* __restrict__ emb,
                                               float* __restrict__ enorm,
                                               int* __restrict__ counts) {
    int k = blockIdx.x * 256 + threadIdx.x;
    const float4* e4 = (const float4*)(emb + (size_t)k * C_);
    float s = 0.f;
#pragma unroll 8
    for (int j = 0; j < C_ / 4; ++j) {
        float4 v = e4[j];
        s += v.x * v.x + v.y * v.y + v.z * v.z + v.w * v.w;
    }
    enorm[k] = s;
    counts[k] = 0;
}

// --------------------------------------------------------- MFMA argmin GEMM
// Block: 64 rows x 1024 codes, 4 waves (16 rows each). A (3 bf16 splits) in
// registers; B (2 splits) double-buffered in LDS via global_load_lds.
// 5-product fp32 emulation: ah*Bh, ah*Bm, am*Bh, am*Bm, al*Bh.
__global__ __launch_bounds__(256, 3) void k_argmin_mfma(const float* __restrict__ x,
                                                        const char* __restrict__ epk,
                                                        const float* __restrict__ enorm,
                                                        int* __restrict__ bestIdx,
                                                        int* __restrict__ counts) {
    __shared__ __align__(16) char Bs[2][16384];
    __shared__ float En[K_];

    const int tid  = threadIdx.x;
    const int lane = tid & 63;
    const int wid  = tid >> 6;
    const int l15  = lane & 15;
    const int kg   = lane >> 4;
    const int row0 = blockIdx.x * 64;
    const int cpOff = wid * 1024 + lane * 16;   // this wave's copy offset (4KB/wave)

    // ---- stage enorm to LDS
    for (int i = tid; i < K_; i += 256) En[i] = enorm[i];

    // ---- build A fragments in registers (row = l15, k-elems = kg*8+i)
    union FU { bf16x8 v; ushort u[8]; };
    FU Ah[8], Am[8], Al[8];
    {
        const int n  = row0 + wid * 16 + l15;
        const int b  = n >> 12, hw = n & 4095;
        const float* xb = x + (size_t)b * (C_ * HW_) + hw;
#pragma unroll
        for (int cb = 0; cb < 8; ++cb) {
#pragma unroll
            for (int i = 0; i < 8; ++i) {
                float v = xb[(cb * 32 + kg * 8 + i) * HW_];
                ushort h, m, l;
                split3(v, h, m, l);
                Ah[cb].u[i] = h; Am[cb].u[i] = m; Al[cb].u[i] = l;
            }
        }
    }
    __syncthreads();   // drains vmcnt(0)+lgkmcnt(0): clean slate for counting

    // ---- stage step 0 (src and dst share the same offset: cpOff+j*4096)
    {
        const char* src = epk + (size_t)cpOff;
        char* dstb = &Bs[0][0] + cpOff;
#pragma unroll
        for (int j = 0; j < 4; ++j) {
            __builtin_amdgcn_global_load_lds(
                (const __attribute__((address_space(1))) void*)(src + j * 4096),
                (__attribute__((address_space(3))) void*)(dstb + j * 4096), 16, 0, 0);
        }
    }

    float best[4] = {FLT_MAX, FLT_MAX, FLT_MAX, FLT_MAX};
    int   bidx[4] = {0, 0, 0, 0};
    const int laneB = kg * 512 + l15 * 16;
    const f32x4 zero = {0.f, 0.f, 0.f, 0.f};
    f32x4 accA, accB;

#define STEP(H, IS_LAST) do {                                                     \
    if (!(IS_LAST)) {                                                             \
        int sn = 2 * kt + (H) + 1;                                                \
        const char* src = epk + (size_t)sn * 16384 + (size_t)cpOff;               \
        char* dstb = &Bs[1 - (H)][0] + cpOff;                                     \
        _Pragma("unroll")                                                         \
        for (int j = 0; j < 4; ++j) {                                             \
            __builtin_amdgcn_global_load_lds(                                     \
                (const __attribute__((address_space(1))) void*)(src + j * 4096),  \
                (__attribute__((address_space(3))) void*)(dstb + j * 4096),       \
                16, 0, 0);                                                        \
        }                                                                         \
        asm volatile("s_waitcnt vmcnt(4)" ::: "memory");                          \
    } else {                                                                      \
        asm volatile("s_waitcnt vmcnt(0)" ::: "memory");                          \
    }                                                                             \
    __builtin_amdgcn_s_barrier();                                                 \
    asm volatile("" ::: "memory");                                                \
    {                                                                             \
        const char* bbase = &Bs[(H)][0] + laneB;                                  \
        _Pragma("unroll")                                                         \
        for (int cbl = 0; cbl < 4; ++cbl) {                                       \
            const char* bp = bbase + cbl * 2048;                                  \
            bf16x8 Bh0 = *(const bf16x8*)(bp);                                    \
            bf16x8 Bm0 = *(const bf16x8*)(bp + 8192);                             \
            bf16x8 Bh1 = *(const bf16x8*)(bp + 256);                              \
            bf16x8 Bm1 = *(const bf16x8*)(bp + 8448);                             \
            const bf16x8 ah = Ah[(H) * 4 + cbl].v;                                \
            const bf16x8 am = Am[(H) * 4 + cbl].v;                                \
            const bf16x8 al = Al[(H) * 4 + cbl].v;                                \
            accA = __builtin_amdgcn_mfma_f32_16x16x32_bf16(ah, Bh0, accA, 0,0,0); \
            accB = __builtin_amdgcn_mfma_f32_16x16x32_bf16(ah, Bh1, accB, 0,0,0); \
            accA = __builtin_amdgcn_mfma_f32_16x16x32_bf16(am, Bh0, accA, 0,0,0); \
            accB = __builtin_amdgcn_mfma_f32_16x16x32_bf16(am, Bh1, accB, 0,0,0); \
            accA = __builtin_amdgcn_mfma_f32_16x16x32_bf16(ah, Bm0, accA, 0,0,0); \
            accB = __builtin_amdgcn_mfma_f32_16x16x32_bf16(ah, Bm1, accB, 0,0,0); \
            accA = __builtin_amdgcn_mfma_f32_16x16x32_bf16(am, Bm0, accA, 0,0,0); \
            accB = __builtin_amdgcn_mfma_f32_16x16x32_bf16(am, Bm1, accB, 0,0,0); \
            accA = __builtin_amdgcn_mfma_f32_16x16x32_bf16(al, Bh0, accA, 0,0,0); \
            accB = __builtin_amdgcn_mfma_f32_16x16x32_bf16(al, Bh1, accB, 0,0,0); \
        }                                                                         \
    }                                                                             \
    asm volatile("s_waitcnt lgkmcnt(0)" ::: "memory");                            \
    __builtin_amdgcn_s_barrier();                                                 \
} while (0)

    for (int kt = 0; kt < 32; ++kt) {
        accA = zero; accB = zero;
        STEP(0, false);
        STEP(1, kt == 31);
        // fold: lane holds cols cA = kt*32+l15 (tile0), cB = cA+16 (tile1);
        // rows = kg*4 + r. Ascending k + strict < => first-occurrence.
        const int cA = kt * 32 + l15;
        const int cB = cA + 16;
        const float enA = En[cA], enB = En[cB];
#pragma unroll
        for (int r = 0; r < 4; ++r) {
            float dA = enA - 2.0f * accA[r];
            if (dA < best[r]) { best[r] = dA; bidx[r] = cA; }
            float dB = enB - 2.0f * accB[r];
            if (dB < best[r]) { best[r] = dB; bidx[r] = cB; }
        }
    }
#undef STEP

    // cross-lane argmin over the 16 cols (lanes sharing kg group)
#pragma unroll
    for (int r = 0; r < 4; ++r) {
        float v  = best[r];
        int   id = bidx[r];
#pragma unroll
        for (int m = 1; m < 16; m <<= 1) {
            float ov = __shfl_xor(v, m);
            int   oi = __shfl_xor(id, m);
            if (ov < v || (ov == v && oi < id)) { v = ov; id = oi; }
        }
        if (l15 == 0) {
            int n = row0 + wid * 16 + kg * 4 + r;
            bestIdx[n] = id;
            atomicAdd(&counts[id], 1);
        }
    }
}

// --------------------------------------------- gather quantized + loss part
__global__ __launch_bounds__(256) void k_quant(const float* __restrict__ x,
                                               const float* __restrict__ emb,
                                               const int* __restrict__ bestIdx,
                                               float* __restrict__ outq,
                                               float* __restrict__ partials) {
    const int tid = threadIdx.x;
    float lsum = 0.f;
#pragma unroll
    for (int it = 0; it < 4; ++it) {
        int q  = blockIdx.x * 256 + tid + it * (4096 * 256);
        int f  = q << 2;
        int hw = f & 4095;
        int c  = (f >> 12) & 255;
        int b  = f >> 20;
        int n0 = (b << 12) + hw;
        int4  id = *(const int4*)&bestIdx[n0];
        float4 xv = *(const float4*)&x[f];
        float q0 = emb[id.x * C_ + c];
        float q1 = emb[id.y * C_ + c];
        float q2 = emb[id.z * C_ + c];
        float q3 = emb[id.w * C_ + c];
        outq[f + 0] = xv.x + (q0 - xv.x);
        outq[f + 1] = xv.y + (q1 - xv.y);
        outq[f + 2] = xv.z + (q2 - xv.z);
        outq[f + 3] = xv.w + (q3 - xv.w);
        float d0 = q0 - xv.x, d1 = q1 - xv.y, d2 = q2 - xv.z, d3 = q3 - xv.w;
        lsum += d0 * d0 + d1 * d1 + d2 * d2 + d3 * d3;
    }
    __shared__ float red[4];
#pragma unroll
    for (int o = 32; o > 0; o >>= 1) lsum += __shfl_down(lsum, o);
    if ((tid & 63) == 0) red[tid >> 6] = lsum;
    __syncthreads();
    if (tid == 0) partials[blockIdx.x] = (red[0] + red[1]) + (red[2] + red[3]);
}

// ------------------------------------------------------- one-hot encodings
// One float4 store per thread per row; 8 rows per block.
__global__ __launch_bounds__(256) void k_enc(const int* __restrict__ bestIdx,
                                             float* __restrict__ enc) {
    const int k4 = threadIdx.x * 4;
    int row = blockIdx.x * 8;
#pragma unroll
    for (int j = 0; j < 8; ++j, ++row) {
        int idv = bestIdx[row];
        float4 v;
        v.x = (k4 + 0 == idv) ? 1.0f : 0.0f;
        v.y = (k4 + 1 == idv) ? 1.0f : 0.0f;
        v.z = (k4 + 2 == idv) ? 1.0f : 0.0f;
        v.w = (k4 + 3 == idv) ? 1.0f : 0.0f;
        *(float4*)&enc[(size_t)row * K_ + k4] = v;
    }
}

// ----------------------------------------------------------------- finalize
__global__ __launch_bounds__(256) void k_final(const float* __restrict__ partials,
                                               const int* __restrict__ counts,
                                               float* __restrict__ out) {
    const int tid = threadIdx.x;
    float s = 0.f;
    for (int i = tid; i < 4096; i += 256) s += partials[i];
    float h = 0.f;
    for (int k = tid; k < K_; k += 256) {
        float p = (float)counts[k] * (1.0f / 65536.0f);
        h += p * logf(p + 1e-10f);
    }
    __shared__ float redS[4], redH[4];
#pragma unroll
    for (int o = 32; o > 0; o >>= 1) {
        s += __shfl_down(s, o);
        h += __shfl_down(h, o);
    }
    if ((tid & 63) == 0) { redS[tid >> 6] = s; redH[tid >> 6] = h; }
    __syncthreads();
    if (tid == 0) {
        float S = (redS[0] + redS[1]) + (redS[2] + redS[3]);
        float H = (redH[0] + redH[1]) + (redH[2] + redH[3]);
        out[0]        = 0.25f * S / 16777216.0f;
        out[OUT_POFF] = expf(-H);
    }
}

extern "C" void kernel_launch(void* const* d_in, const int* in_sizes, int n_in,
                              void* d_out, int out_size, void* d_ws, size_t ws_size,
                              hipStream_t stream) {
    const float* x   = (const float*)d_in[0];
    const float* emb = (const float*)d_in[1];
    float* out = (float*)d_out;
    char*  ws  = (char*)d_ws;

    // Workspace layout
    int*   bestIdx  = (int*)(ws);                 // 262144 B
    int*   counts   = (int*)(ws + 262144);        //   4096 B
    float* partials = (float*)(ws + 266240);      //  16384 B
    float* enorm    = (float*)(ws + 282624);      //   4096 B
    char*  epk      = ws + 286720;                // 1048576 B packed e-splits (2-way)

    k_pack_e     <<<K_ * C_ / 256, 256, 0, stream>>>(emb, epk);
    k_enorm      <<<K_ / 256,      256, 0, stream>>>(emb, enorm, counts);
    k_argmin_mfma<<<N_ / 64,       256, 0, stream>>>(x, epk, enorm, bestIdx, counts);
    k_quant      <<<4096,          256, 0, stream>>>(x, emb, bestIdx, out + OUT_QOFF, partials);
    k_enc        <<<8192,          256, 0, stream>>>(bestIdx, out + OUT_EOFF);
    k_final      <<<1,             256, 0, stream>>>(partials, counts, out);
}

// Round 6
// 252.346 us; speedup vs baseline: 3.9167x; 1.0365x over previous
//
#include <hip/hip_runtime.h>
#include <cfloat>

// Problem constants
#define B_   16
#define C_   256
#define HW_  4096      // 64*64
#define N_   65536     // B_*HW_
#define K_   1024

// Output layout (float32, concatenated flat in return order):
//  [0] loss | [1,+16777216) quantized (b c h w) | [16777217] perplexity
//  [16777218,+67108864) encodings (N,K)
#define OUT_QOFF   1
#define OUT_POFF   16777217
#define OUT_EOFF   16777218

typedef __bf16 bf16x8 __attribute__((ext_vector_type(8)));
typedef float  f32x4  __attribute__((ext_vector_type(4)));

// ---------------------------------------------------------------- bf16 split
__device__ inline ushort f2bf(float f) {
    union { float f; unsigned u; } a; a.f = f;
    unsigned u = a.u;
    unsigned r = (u + 0x7fffu + ((u >> 16) & 1u)) >> 16;   // RNE
    return (ushort)r;
}
__device__ inline float bf2f(ushort u) {
    union { float f; unsigned u; } a; a.u = ((unsigned)u) << 16; return a.f;
}

// ------------------------------------- prep: pack e (2-split) + enorm + cnt0
// One block per code k; thread c handles channel c.
// Packed layout per step s in [0,64): s = (k>>5)*2 + (c>>7); within 16384-B
// block: [split(2)][cg(16)][code(32)][ci(8)] bf16.
__global__ __launch_bounds__(256) void k_prep(const float* __restrict__ emb,
                                              char* __restrict__ epk,
                                              float* __restrict__ enorm,
                                              int* __restrict__ counts) {
    const int k = blockIdx.x;
    const int c = threadIdx.x;
    float v = emb[k * C_ + c];
    ushort h = f2bf(v);
    ushort m = f2bf(v - bf2f(h));
    int s  = (k >> 5) * 2 + (c >> 7);
    int cl = c & 127;
    size_t off = (size_t)s * 16384 + (size_t)((cl >> 3) * 512 + (k & 31) * 16 + (cl & 7) * 2);
    *(ushort*)(epk + off)        = h;
    *(ushort*)(epk + off + 8192) = m;
    // block-reduce v^2 -> enorm[k]
    float sq = v * v;
    __shared__ float red[4];
#pragma unroll
    for (int o = 32; o > 0; o >>= 1) sq += __shfl_down(sq, o);
    if ((c & 63) == 0) red[c >> 6] = sq;
    __syncthreads();
    if (c == 0) {
        enorm[k]  = (red[0] + red[1]) + (red[2] + red[3]);
        counts[k] = 0;
    }
}

// --------------------------------------------------------- MFMA argmin GEMM
// Block: 128 rows x 1024 codes, 4 waves (32 rows each = 2 row-frags of 16).
// A (2 bf16 splits) in registers; B (2 splits) double-buffered in LDS via
// global_load_lds. 4-product fp32 emulation: ah*Bh, ah*Bm, am*Bh, am*Bm.
__global__ __launch_bounds__(256, 2) void k_argmin_mfma(const float* __restrict__ x,
                                                        const char* __restrict__ epk,
                                                        const float* __restrict__ enorm,
                                                        int* __restrict__ bestIdx,
                                                        int* __restrict__ counts) {
    __shared__ __align__(16) char Bs[2][16384];
    __shared__ float En[K_];

    const int tid  = threadIdx.x;
    const int lane = tid & 63;
    const int wid  = tid >> 6;
    const int l15  = lane & 15;
    const int kg   = lane >> 4;
    const int row0 = blockIdx.x * 128;
    const int cpOff = wid * 1024 + lane * 16;   // this wave's copy offset (4KB/wave)

    // ---- stage enorm to LDS
    for (int i = tid; i < K_; i += 256) En[i] = enorm[i];

    // ---- build A fragments in registers: frag f rows = wid*32+f*16+l15,
    //      k-elems = kg*8+i within each 32-channel window cb
    union FU { bf16x8 v; ushort u[8]; };
    FU Ah[2][8], Am[2][8];
#pragma unroll
    for (int f = 0; f < 2; ++f) {
        const int n  = row0 + wid * 32 + f * 16 + l15;
        const int b  = n >> 12, hw = n & 4095;
        const float* xb = x + (size_t)b * (C_ * HW_) + hw;
#pragma unroll
        for (int cb = 0; cb < 8; ++cb) {
#pragma unroll
            for (int i = 0; i < 8; ++i) {
                float v = xb[(cb * 32 + kg * 8 + i) * HW_];
                ushort h = f2bf(v);
                ushort m = f2bf(v - bf2f(h));
                Ah[f][cb].u[i] = h; Am[f][cb].u[i] = m;
            }
        }
    }
    __syncthreads();   // drains vmcnt(0)+lgkmcnt(0): clean slate for counting

    // ---- stage step 0 (src and dst share the same offset: cpOff+j*4096)
    {
        const char* src = epk + (size_t)cpOff;
        char* dstb = &Bs[0][0] + cpOff;
#pragma unroll
        for (int j = 0; j < 4; ++j) {
            __builtin_amdgcn_global_load_lds(
                (const __attribute__((address_space(1))) void*)(src + j * 4096),
                (__attribute__((address_space(3))) void*)(dstb + j * 4096), 16, 0, 0);
        }
    }

    float best[2][4] = {{FLT_MAX, FLT_MAX, FLT_MAX, FLT_MAX},
                        {FLT_MAX, FLT_MAX, FLT_MAX, FLT_MAX}};
    int   bidx[2][4] = {{0,0,0,0},{0,0,0,0}};
    const int laneB = kg * 512 + l15 * 16;
    const f32x4 zero = {0.f, 0.f, 0.f, 0.f};
    f32x4 accA0, accB0, accA1, accB1;

#define STEP(H, IS_LAST) do {                                                       \
    if (!(IS_LAST)) {                                                               \
        int sn = 2 * kt + (H) + 1;                                                  \
        const char* src = epk + (size_t)sn * 16384 + (size_t)cpOff;                 \
        char* dstb = &Bs[1 - (H)][0] + cpOff;                                       \
        _Pragma("unroll")                                                           \
        for (int j = 0; j < 4; ++j) {                                               \
            __builtin_amdgcn_global_load_lds(                                       \
                (const __attribute__((address_space(1))) void*)(src + j * 4096),    \
                (__attribute__((address_space(3))) void*)(dstb + j * 4096),         \
                16, 0, 0);                                                          \
        }                                                                           \
        asm volatile("s_waitcnt vmcnt(4)" ::: "memory");                            \
    } else {                                                                        \
        asm volatile("s_waitcnt vmcnt(0)" ::: "memory");                            \
    }                                                                               \
    __builtin_amdgcn_s_barrier();                                                   \
    asm volatile("" ::: "memory");                                                  \
    {                                                                               \
        const char* bbase = &Bs[(H)][0] + laneB;                                    \
        _Pragma("unroll")                                                           \
        for (int cbl = 0; cbl < 4; ++cbl) {                                         \
            const char* bp = bbase + cbl * 2048;                                    \
            bf16x8 Bh0 = *(const bf16x8*)(bp);                                      \
            bf16x8 Bm0 = *(const bf16x8*)(bp + 8192);                               \
            bf16x8 Bh1 = *(const bf16x8*)(bp + 256);                                \
            bf16x8 Bm1 = *(const bf16x8*)(bp + 8448);                               \
            const bf16x8 a0h = Ah[0][(H) * 4 + cbl].v;                              \
            const bf16x8 a0m = Am[0][(H) * 4 + cbl].v;                              \
            const bf16x8 a1h = Ah[1][(H) * 4 + cbl].v;                              \
            const bf16x8 a1m = Am[1][(H) * 4 + cbl].v;                              \
            accA0 = __builtin_amdgcn_mfma_f32_16x16x32_bf16(a0h, Bh0, accA0, 0,0,0);\
            accB0 = __builtin_amdgcn_mfma_f32_16x16x32_bf16(a0h, Bh1, accB0, 0,0,0);\
            accA1 = __builtin_amdgcn_mfma_f32_16x16x32_bf16(a1h, Bh0, accA1, 0,0,0);\
            accB1 = __builtin_amdgcn_mfma_f32_16x16x32_bf16(a1h, Bh1, accB1, 0,0,0);\
            accA0 = __builtin_amdgcn_mfma_f32_16x16x32_bf16(a0m, Bh0, accA0, 0,0,0);\
            accB0 = __builtin_amdgcn_mfma_f32_16x16x32_bf16(a0m, Bh1, accB0, 0,0,0);\
            accA1 = __builtin_amdgcn_mfma_f32_16x16x32_bf16(a1m, Bh0, accA1, 0,0,0);\
            accB1 = __builtin_amdgcn_mfma_f32_16x16x32_bf16(a1m, Bh1, accB1, 0,0,0);\
            accA0 = __builtin_amdgcn_mfma_f32_16x16x32_bf16(a0h, Bm0, accA0, 0,0,0);\
            accB0 = __builtin_amdgcn_mfma_f32_16x16x32_bf16(a0h, Bm1, accB0, 0,0,0);\
            accA1 = __builtin_amdgcn_mfma_f32_16x16x32_bf16(a1h, Bm0, accA1, 0,0,0);\
            accB1 = __builtin_amdgcn_mfma_f32_16x16x32_bf16(a1h, Bm1, accB1, 0,0,0);\
            accA0 = __builtin_amdgcn_mfma_f32_16x16x32_bf16(a0m, Bm0, accA0, 0,0,0);\
            accB0 = __builtin_amdgcn_mfma_f32_16x16x32_bf16(a0m, Bm1, accB0, 0,0,0);\
            accA1 = __builtin_amdgcn_mfma_f32_16x16x32_bf16(a1m, Bm0, accA1, 0,0,0);\
            accB1 = __builtin_amdgcn_mfma_f32_16x16x32_bf16(a1m, Bm1, accB1, 0,0,0);\
        }                                                                           \
    }                                                                               \
    asm volatile("s_waitcnt lgkmcnt(0)" ::: "memory");                              \
    __builtin_amdgcn_s_barrier();                                                   \
} while (0)

    for (int kt = 0; kt < 32; ++kt) {
        accA0 = zero; accB0 = zero; accA1 = zero; accB1 = zero;
        STEP(0, false);
        STEP(1, kt == 31);
        // fold: lane holds cols cA = kt*32+l15 (tile0), cB = cA+16 (tile1);
        // frag f rows = f*16 + kg*4 + r. Ascending k + strict < => first-occ.
        const int cA = kt * 32 + l15;
        const int cB = cA + 16;
        const float enA = En[cA], enB = En[cB];
#pragma unroll
        for (int r = 0; r < 4; ++r) {
            float dA0 = enA - 2.0f * accA0[r];
            if (dA0 < best[0][r]) { best[0][r] = dA0; bidx[0][r] = cA; }
            float dB0 = enB - 2.0f * accB0[r];
            if (dB0 < best[0][r]) { best[0][r] = dB0; bidx[0][r] = cB; }
            float dA1 = enA - 2.0f * accA1[r];
            if (dA1 < best[1][r]) { best[1][r] = dA1; bidx[1][r] = cA; }
            float dB1 = enB - 2.0f * accB1[r];
            if (dB1 < best[1][r]) { best[1][r] = dB1; bidx[1][r] = cB; }
        }
    }
#undef STEP

    // cross-lane argmin over the 16 cols (lanes sharing kg group)
#pragma unroll
    for (int f = 0; f < 2; ++f) {
#pragma unroll
        for (int r = 0; r < 4; ++r) {
            float v  = best[f][r];
            int   id = bidx[f][r];
#pragma unroll
            for (int m = 1; m < 16; m <<= 1) {
                float ov = __shfl_xor(v, m);
                int   oi = __shfl_xor(id, m);
                if (ov < v || (ov == v && oi < id)) { v = ov; id = oi; }
            }
            if (l15 == 0) {
                int n = row0 + wid * 32 + f * 16 + kg * 4 + r;
                bestIdx[n] = id;
                atomicAdd(&counts[id], 1);
            }
        }
    }
}

// --------------------------------------------- gather quantized + loss part
__global__ __launch_bounds__(256) void k_quant(const float* __restrict__ x,
                                               const float* __restrict__ emb,
                                               const int* __restrict__ bestIdx,
                                               float* __restrict__ outq,
                                               float* __restrict__ partials) {
    const int tid = threadIdx.x;
    float lsum = 0.f;
#pragma unroll
    for (int it = 0; it < 4; ++it) {
        int q  = blockIdx.x * 256 + tid + it * (4096 * 256);
        int f  = q << 2;
        int hw = f & 4095;
        int c  = (f >> 12) & 255;
        int b  = f >> 20;
        int n0 = (b << 12) + hw;
        int4  id = *(const int4*)&bestIdx[n0];
        float4 xv = *(const float4*)&x[f];
        float q0 = emb[id.x * C_ + c];
        float q1 = emb[id.y * C_ + c];
        float q2 = emb[id.z * C_ + c];
        float q3 = emb[id.w * C_ + c];
        f32x4 ov;
        ov.x = xv.x + (q0 - xv.x);
        ov.y = xv.y + (q1 - xv.y);
        ov.z = xv.z + (q2 - xv.z);
        ov.w = xv.w + (q3 - xv.w);
        __builtin_nontemporal_store(ov, (f32x4*)&outq[f]);
        float d0 = q0 - xv.x, d1 = q1 - xv.y, d2 = q2 - xv.z, d3 = q3 - xv.w;
        lsum += d0 * d0 + d1 * d1 + d2 * d2 + d3 * d3;
    }
    __shared__ float red[4];
#pragma unroll
    for (int o = 32; o > 0; o >>= 1) lsum += __shfl_down(lsum, o);
    if ((tid & 63) == 0) red[tid >> 6] = lsum;
    __syncthreads();
    if (tid == 0) partials[blockIdx.x] = (red[0] + red[1]) + (red[2] + red[3]);
}

// ------------------------------------------------------- one-hot encodings
// One f32x4 nontemporal store per thread per row; 8 rows per block.
__global__ __launch_bounds__(256) void k_enc(const int* __restrict__ bestIdx,
                                             float* __restrict__ enc) {
    const int k4 = threadIdx.x * 4;
    int row = blockIdx.x * 8;
#pragma unroll
    for (int j = 0; j < 8; ++j, ++row) {
        int idv = bestIdx[row];
        f32x4 v;
        v.x = (k4 + 0 == idv) ? 1.0f : 0.0f;
        v.y = (k4 + 1 == idv) ? 1.0f : 0.0f;
        v.z = (k4 + 2 == idv) ? 1.0f : 0.0f;
        v.w = (k4 + 3 == idv) ? 1.0f : 0.0f;
        __builtin_nontemporal_store(v, (f32x4*)&enc[(size_t)row * K_ + k4]);
    }
}

// ----------------------------------------------------------------- finalize
__global__ __launch_bounds__(256) void k_final(const float* __restrict__ partials,
                                               const int* __restrict__ counts,
                                               float* __restrict__ out) {
    const int tid = threadIdx.x;
    float s = 0.f;
    for (int i = tid; i < 4096; i += 256) s += partials[i];
    float h = 0.f;
    for (int k = tid; k < K_; k += 256) {
        float p = (float)counts[k] * (1.0f / 65536.0f);
        h += p * logf(p + 1e-10f);
    }
    __shared__ float redS[4], redH[4];
#pragma unroll
    for (int o = 32; o > 0; o >>= 1) {
        s += __shfl_down(s, o);
        h += __shfl_down(h, o);
    }
    if ((tid & 63) == 0) { redS[tid >> 6] = s; redH[tid >> 6] = h; }
    __syncthreads();
    if (tid == 0) {
        float S = (redS[0] + redS[1]) + (redS[2] + redS[3]);
        float H = (redH[0] + redH[1]) + (redH[2] + redH[3]);
        out[0]        = 0.25f * S / 16777216.0f;
        out[OUT_POFF] = expf(-H);
    }
}

extern "C" void kernel_launch(void* const* d_in, const int* in_sizes, int n_in,
                              void* d_out, int out_size, void* d_ws, size_t ws_size,
                              hipStream_t stream) {
    const float* x   = (const float*)d_in[0];
    const float* emb = (const float*)d_in[1];
    float* out = (float*)d_out;
    char*  ws  = (char*)d_ws;

    // Workspace layout
    int*   bestIdx  = (int*)(ws);                 // 262144 B
    int*   counts   = (int*)(ws + 262144);        //   4096 B
    float* partials = (float*)(ws + 266240);      //  16384 B
    float* enorm    = (float*)(ws + 282624);      //   4096 B
    char*  epk      = ws + 286720;                // 1048576 B packed e-splits (2-way)

    k_prep       <<<K_,       256, 0, stream>>>(emb, epk, enorm, counts);
    k_argmin_mfma<<<N_ / 128, 256, 0, stream>>>(x, epk, enorm, bestIdx, counts);
    k_quant      <<<4096,     256, 0, stream>>>(x, emb, bestIdx, out + OUT_QOFF, partials);
    k_enc        <<<8192,     256, 0, stream>>>(bestIdx, out + OUT_EOFF);
    k_final      <<<1,        256, 0, stream>>>(partials, counts, out);
}